// Round 11
// baseline (198.338 us; speedup 1.0000x reference)
//
#include <hip/hip_runtime.h>
#include <stdint.h>

#define L_NR 192
#define S_NS 256
#define D_   256
#define H_   8
#define C_   32

typedef __bf16    bf16x8_t __attribute__((ext_vector_type(8)));
typedef _Float16  half4_t  __attribute__((ext_vector_type(4)));
typedef float     f32x4_t  __attribute__((ext_vector_type(4)));

__device__ __forceinline__ float bflo(unsigned int u) { return __uint_as_float(u << 16); }
__device__ __forceinline__ unsigned int f2b(float f) {
    unsigned int x = __float_as_uint(f);
    return (x + 0x7fffu + ((x >> 16) & 1u)) >> 16;   // RNE
}
__device__ __forceinline__ unsigned short f2h(float f) {
    union { _Float16 h; unsigned short u; } cv; cv.h = (_Float16)f; return cv.u;
}

// ---- LayerNorm (blocks 0..12287) + weight bf16 conversion (blocks 12288..12607) ----
__global__ __launch_bounds__(256) void ln_convw_kernel(
    const float* __restrict__ m,
    const float* __restrict__ lns,
    const float* __restrict__ lnb,
    unsigned short* __restrict__ xn,
    const float* __restrict__ wq, const float* __restrict__ wk,
    const float* __restrict__ wv, const float* __restrict__ wg,
    const float* __restrict__ wo, unsigned short* __restrict__ wbf)
{
    int tid = threadIdx.x;
    int b = blockIdx.x;

    if (b >= 12288) {                       // ---- convw part ----
        int cb  = b - 12288;                // 0..319
        int mat = cb >> 6;                  // 64 blocks per matrix
        int bx  = cb & 63;
        const float* src = (mat == 0) ? wq : (mat == 1) ? wk : (mat == 2) ? wv
                         : (mat == 3) ? wg : wo;
        int i = (bx * 256 + tid) * 4;
        float4 v = *(const float4*)(src + i);
        uint2 w;
        w.x = f2b(v.x) | (f2b(v.y) << 16);
        w.y = f2b(v.z) | (f2b(v.w) << 16);
        *(uint2*)(wbf + (size_t)mat * 65536 + i) = w;
        return;
    }

    // ---- layernorm part: m fp32 (S,L,D) -> xn bf16 (L,S,D) ----
    int lane = tid & 63, wave = tid >> 6;
    int r = b * 4 + wave;                   // r = s*L + l
    int s = r / L_NR, l = r % L_NR;

    float4 x = ((const float4*)(m + (size_t)r * D_))[lane];

    float sum = x.x + x.y + x.z + x.w;
    float ss  = x.x*x.x + x.y*x.y + x.z*x.z + x.w*x.w;
#pragma unroll
    for (int off = 32; off > 0; off >>= 1) {
        sum += __shfl_xor(sum, off, 64);
        ss  += __shfl_xor(ss,  off, 64);
    }
    float mean = sum * (1.0f/256.0f);
    float var  = ss  * (1.0f/256.0f) - mean * mean;
    float rstd = rsqrtf(fmaxf(var, 0.0f) + 1e-5f);

    float4 sc = ((const float4*)lns)[lane];
    float4 bi = ((const float4*)lnb)[lane];

    float y0 = (x.x - mean) * rstd * sc.x + bi.x;
    float y1 = (x.y - mean) * rstd * sc.y + bi.y;
    float y2 = (x.z - mean) * rstd * sc.z + bi.z;
    float y3 = (x.w - mean) * rstd * sc.w + bi.w;

    uint2 w;
    w.x = f2b(y0) | (f2b(y1) << 16);
    w.y = f2b(y2) | (f2b(y3) << 16);
    *(uint2*)(xn + ((size_t)l * S_NS + s) * D_ + lane * 4) = w;
}

// ------------- Fused projections + attention per (l,h) -------------
// Round-11 (VALU work-reduction; kernel is ~85% issue-saturated per r10 PMC):
//  * flagall fast path: when no masking applies (block-uniform, ~50%+ of
//    blocks with random pads), drop the 3-op/value mask sequence entirely.
//  * g==0 specialization: first group's deferred-rescale always fired with
//    f=exp2(-3e38)=0 on zero state -> replaced by mk=gmk (bit-identical).
//  * T5 s_setprio(1) around MFMA clusters: 2 resident blocks/CU sit at
//    different phases (GEMM vs attn) -> scheduler role-diversity exists.
// All transformations bit-identical -> absmax must stay 0.004882812.
#define QP 40    // Q/K LDS row stride (bf16 elems)
#define VP 264   // V^T LDS row stride (f16 elems)
#define VXOR(c) (((((c) >> 3) & 3)) << 4)

__global__ __launch_bounds__(512, 4) void fused_kernel(
    const unsigned short* __restrict__ xn,
    const unsigned short* __restrict__ wbf,   // 4 matrices, bf16, 65536 each
    const float* __restrict__ bg,
    const int* __restrict__ seq_pad, const int* __restrict__ res_pad,
    unsigned short* __restrict__ ctxg)
{
    __shared__ __align__(16) unsigned char SM[65536];   // union: Bst | {Q,K,V}
    __shared__ unsigned int padm[16];

    unsigned short* Bst  = (unsigned short*)SM;               // 65536 B (GEMM phase)
    unsigned short* Qlds = (unsigned short*)SM;               // 20480 B (attn phase)
    unsigned short* Klds = (unsigned short*)(SM + 20480);     // 20480 B
    unsigned short* Vlds = (unsigned short*)(SM + 40960);     // 16896 B (ends 57856)

    int tid  = threadIdx.x;
    int lane = tid & 63, wave = tid >> 6;       // 8 waves
    int quad = lane >> 4, l16 = lane & 15;

    // XCD regroup: the 8 h-blocks of one l are consecutive slots on ONE XCD.
    int hw   = blockIdx.x;
    int xcd  = hw & 7, slot = hw >> 3;
    int h    = slot & 7;
    int l    = (slot >> 3) * 8 + xcd;

    if (tid < 16) {
        unsigned int pm = 0;
        for (int mt = 0; mt < 16; ++mt)
            pm |= (seq_pad[mt * 16 + tid] != 0 ? 1u : 0u) << mt;
        padm[tid] = pm;
    }

    int row0 = l * 256 + wave * 32;
    const unsigned short* arow = xn + (size_t)(row0 + l16) * D_ + quad * 8;

    // early A prefetch for ks=0 (completes during staging)
    bf16x8_t a_cur[2], a_nxt[2];
    a_cur[0] = *(const bf16x8_t*)(arow);
    a_cur[1] = *(const bf16x8_t*)(arow + 16 * D_);

    // stage all 4 B tiles (32 n x 256 k each): coalesced global, swizzled LDS
    const unsigned short* Wh = wbf + (size_t)(h * 32) * 256;
#pragma unroll
    for (int j = 0; j < 8; ++j) {
        int mat = j >> 1;
        int c  = (j & 1) * 512 + tid;
        int n  = c >> 5, kk = c & 31;
        int ks = kk >> 2, kq = kk & 3;
        int sw = (n & 15) ^ kq ^ ((ks & 1) << 2);
        uint4 d = *(const uint4*)(Wh + (size_t)mat * 65536 + n * 256 + kk * 8);
        *(uint4*)&Bst[mat * 8192 + ks * 1024 + (n >> 4) * 512 + kq * 128 + sw * 8] = d;
    }
    __syncthreads();

    f32x4_t acc[4][2][2];
#pragma unroll
    for (int mat = 0; mat < 4; ++mat)
#pragma unroll
        for (int mt = 0; mt < 2; ++mt)
#pragma unroll
            for (int nt = 0; nt < 2; ++nt) acc[mat][mt][nt] = (f32x4_t){0.f,0.f,0.f,0.f};

    int swb = l16 ^ quad;
#pragma unroll
    for (int ks = 0; ks < 8; ++ks) {
        if (ks < 7) {
            a_nxt[0] = *(const bf16x8_t*)(arow + (ks + 1) * 32);
            a_nxt[1] = *(const bf16x8_t*)(arow + 16 * D_ + (ks + 1) * 32);
        }
        int kbase = ks * 1024 + quad * 128 + (swb ^ ((ks & 1) << 2)) * 8;
        __builtin_amdgcn_s_setprio(1);
#pragma unroll
        for (int mat = 0; mat < 4; ++mat) {
#pragma unroll
            for (int nt = 0; nt < 2; ++nt) {
                bf16x8_t bfr = *(const bf16x8_t*)&Bst[mat * 8192 + kbase + nt * 512];
                acc[mat][0][nt] = __builtin_amdgcn_mfma_f32_16x16x32_bf16(a_cur[0], bfr, acc[mat][0][nt], 0, 0, 0);
                acc[mat][1][nt] = __builtin_amdgcn_mfma_f32_16x16x32_bf16(a_cur[1], bfr, acc[mat][1][nt], 0, 0, 0);
            }
        }
        __builtin_amdgcn_s_setprio(0);
        a_cur[0] = a_nxt[0]; a_cur[1] = a_nxt[1];
    }
    __syncthreads();   // ALL waves done reading Bst before Q/K/V overwrite it

    // ---- epilogues: write Q/K/V into the union region + gate regs ----
    const float qscale = 0.17677669529663687f;  // 1/sqrt(32)
    f32x4_t accg[2][2];

#pragma unroll
    for (int mt = 0; mt < 2; ++mt)
#pragma unroll
        for (int nt = 0; nt < 2; ++nt) {
#pragma unroll
            for (int r = 0; r < 4; ++r) {
                int srow = wave * 32 + mt * 16 + quad * 4 + r;
                Qlds[srow * QP + nt * 16 + l16] = (unsigned short)f2b(acc[0][mt][nt][r] * qscale);
                Klds[srow * QP + nt * 16 + l16] = (unsigned short)f2b(acc[1][mt][nt][r]);
            }
            // V: f16, transposed + swizzled, b64 packed
            int cc = nt * 16 + l16;
            int s0 = wave * 32 + mt * 16 + quad * 4;
            half4_t hv;
            hv[0] = (_Float16)acc[2][mt][nt][0];
            hv[1] = (_Float16)acc[2][mt][nt][1];
            hv[2] = (_Float16)acc[2][mt][nt][2];
            hv[3] = (_Float16)acc[2][mt][nt][3];
            *(half4_t*)&Vlds[cc * VP + (s0 ^ VXOR(cc))] = hv;
            // G: sigmoid, round through bf16, keep in regs
            float bgn = bg[h * 32 + nt * 16 + l16];
#pragma unroll
            for (int r = 0; r < 4; ++r)
                accg[mt][nt][r] = bflo(f2b(1.0f / (1.0f + __expf(-(acc[3][mt][nt][r] + bgn)))));
        }
    __syncthreads();   // K/V/Q (cross-wave) complete before attention reads

    // ---------------- attention (2 qt x 16 rows/wave, online softmax) ----
    unsigned int allm = 0xFFFFu;
#pragma unroll
    for (int i = 0; i < 16; ++i) allm &= padm[i];
    int flagall = (res_pad[l] != 0) || (allm == 0xFFFFu);

    unsigned int keep[4];
#pragma unroll
    for (int r = 0; r < 4; ++r)
        keep[r] = flagall ? 0xFFFFu : (~padm[quad * 4 + r] & 0xFFFFu);

    const float LOG2E = 1.4426950408889634f;
    int vx0 = VXOR(l16), vx1 = VXOR(16 + l16);

#pragma unroll
    for (int qt = 0; qt < 2; ++qt) {
        int sb = wave * 32 + qt * 16;

        bf16x8_t qf = *(const bf16x8_t*)(Qlds + (size_t)(sb + l16) * QP + quad * 8);

        float mk = -3.0e38f;
        float sp = 0.0f;
        f32x4_t c0 = (f32x4_t){0.f,0.f,0.f,0.f}, c1 = (f32x4_t){0.f,0.f,0.f,0.f};

#pragma unroll
        for (int g = 0; g < 2; ++g) {
            f32x4_t a[8];
            __builtin_amdgcn_s_setprio(1);
#pragma unroll
            for (int j = 0; j < 8; ++j) {
                int kt = g * 8 + j;
                bf16x8_t kf = *(const bf16x8_t*)(Klds + (kt * 16 + l16) * QP + quad * 8);
                a[j] = __builtin_amdgcn_mfma_f32_16x16x32_bf16(kf, qf, (f32x4_t){0.f,0.f,0.f,0.f}, 0, 0, 0);
            }
            __builtin_amdgcn_s_setprio(0);
            float p0 = fmaxf(fmaxf(a[0][0], a[0][1]), fmaxf(a[0][2], a[0][3]));
            float p1 = fmaxf(fmaxf(a[1][0], a[1][1]), fmaxf(a[1][2], a[1][3]));
            float p2 = fmaxf(fmaxf(a[2][0], a[2][1]), fmaxf(a[2][2], a[2][3]));
            float p3 = fmaxf(fmaxf(a[3][0], a[3][1]), fmaxf(a[3][2], a[3][3]));
            float p4 = fmaxf(fmaxf(a[4][0], a[4][1]), fmaxf(a[4][2], a[4][3]));
            float p5 = fmaxf(fmaxf(a[5][0], a[5][1]), fmaxf(a[5][2], a[5][3]));
            float p6 = fmaxf(fmaxf(a[6][0], a[6][1]), fmaxf(a[6][2], a[6][3]));
            float p7 = fmaxf(fmaxf(a[7][0], a[7][1]), fmaxf(a[7][2], a[7][3]));
            float gm = fmaxf(fmaxf(fmaxf(p0, p1), fmaxf(p2, p3)),
                             fmaxf(fmaxf(p4, p5), fmaxf(p6, p7)));
            gm = fmaxf(gm, __shfl_xor(gm, 16, 64));
            gm = fmaxf(gm, __shfl_xor(gm, 32, 64));
            float gmk = gm * LOG2E;

            if (g == 0) {
                // first group: c0/c1/sp are zero; old path multiplied them by
                // exp2(-3e38-gmk)==0 — equivalent to just adopting gmk.
                mk = gmk;
            } else {
                bool need = gmk > mk + 11.0f;
                if (__any(need)) {
                    float nmk = fmaxf(mk, gmk);
                    float f = __builtin_amdgcn_exp2f(mk - nmk);
                    mk = nmk;
                    sp *= f;
#pragma unroll
                    for (int r = 0; r < 4; ++r) {
                        float fr = __shfl(f, (lane & 48) | (quad * 4 + r), 64);
                        c0[r] *= fr; c1[r] *= fr;
                    }
                }
            }

            half4_t pf[8];
            float s0 = 0.f, s1 = 0.f, s2 = 0.f, s3 = 0.f;
            if (flagall) {
                // fast path: no masking (keep == 0xFFFF for every row)
#pragma unroll
                for (int j = 0; j < 8; ++j) {
                    float e0 = __builtin_amdgcn_exp2f(a[j][0] * LOG2E - mk);
                    float e1 = __builtin_amdgcn_exp2f(a[j][1] * LOG2E - mk);
                    float e2 = __builtin_amdgcn_exp2f(a[j][2] * LOG2E - mk);
                    float e3 = __builtin_amdgcn_exp2f(a[j][3] * LOG2E - mk);
                    s0 += e0; s1 += e1; s2 += e2; s3 += e3;
                    half4_t t;
                    t[0] = (_Float16)e0; t[1] = (_Float16)e1;
                    t[2] = (_Float16)e2; t[3] = (_Float16)e3;
                    pf[j] = t;
                }
            } else {
#pragma unroll
                for (int j = 0; j < 8; ++j) {
                    int kt = g * 8 + j;
                    float e0 = __builtin_amdgcn_exp2f(a[j][0] * LOG2E - mk);
                    float e1 = __builtin_amdgcn_exp2f(a[j][1] * LOG2E - mk);
                    float e2 = __builtin_amdgcn_exp2f(a[j][2] * LOG2E - mk);
                    float e3 = __builtin_amdgcn_exp2f(a[j][3] * LOG2E - mk);
                    e0 = ((keep[0] >> kt) & 1u) ? e0 : 0.0f;
                    e1 = ((keep[1] >> kt) & 1u) ? e1 : 0.0f;
                    e2 = ((keep[2] >> kt) & 1u) ? e2 : 0.0f;
                    e3 = ((keep[3] >> kt) & 1u) ? e3 : 0.0f;
                    s0 += e0; s1 += e1; s2 += e2; s3 += e3;
                    half4_t t;
                    t[0] = (_Float16)e0; t[1] = (_Float16)e1;
                    t[2] = (_Float16)e2; t[3] = (_Float16)e3;
                    pf[j] = t;
                }
            }
            sp += (s0 + s1) + (s2 + s3);

            __builtin_amdgcn_s_setprio(1);
#pragma unroll
            for (int j = 0; j < 8; ++j) {
                int kt = g * 8 + j;
                int toff = kt * 16 + quad * 4;
                half4_t v0 = *(const half4_t*)(Vlds + l16 * VP        + (toff ^ vx0));
                half4_t v1 = *(const half4_t*)(Vlds + (16 + l16) * VP + (toff ^ vx1));
                c0 = __builtin_amdgcn_mfma_f32_16x16x16f16(pf[j], v0, c0, 0, 0, 0);
                c1 = __builtin_amdgcn_mfma_f32_16x16x16f16(pf[j], v1, c1, 0, 0, 0);
            }
            __builtin_amdgcn_s_setprio(0);
        }

        sp += __shfl_xor(sp, 16, 64);
        sp += __shfl_xor(sp, 32, 64);
        float inv = 1.0f / sp;

#pragma unroll
        for (int r = 0; r < 4; ++r) {
            int s = sb + quad * 4 + r;
            float iv = __shfl(inv, (lane & 48) | (quad * 4 + r), 64);
            float g0 = accg[qt][0][r];
            float g1 = accg[qt][1][r];
            unsigned short* op = ctxg + (size_t)(l * S_NS + s) * D_ + h * C_;
            op[l16]      = (unsigned short)f2b(c0[r] * iv * g0);
            op[16 + l16] = (unsigned short)f2b(c1[r] * iv * g1);
        }
    }
}

// ------------- Output projection (LDS-B): ctxg @ wo^T + bo -> out fp32 (S,L,D) -------------
// Round-9 structure kept: coalesced LDS-transpose epilogue, (256,4), XCD regroup.
__global__ __launch_bounds__(256, 4) void out_kernel(
    const unsigned short* __restrict__ ctxg,
    const unsigned short* __restrict__ wob,   // bf16 wo
    const float* __restrict__ bo,
    float* __restrict__ out)
{
    __shared__ __align__(16) unsigned char OSM[34816];   // union: B (32KB) | T [128][68] f32
    unsigned short* Bl = (unsigned short*)OSM;
    float*          T  = (float*)OSM;

    int tid  = threadIdx.x;
    int lane = tid & 63, wave = tid >> 6;
    int quad = lane >> 4, l16 = lane & 15;

    // --- XCD regroup: invert hw = l%8 + 8*((l/8)*4 + y) ---
    int hw   = blockIdx.y * 192 + blockIdx.x;   // dispatch index (x-fastest)
    int xcd  = hw & 7;
    int slot = hw >> 3;
    int y    = slot & 3;
    int l    = (slot >> 2) * 8 + xcd;

    int n0   = y * 64;
    const unsigned short* W = wob + (size_t)n0 * 256;

#pragma unroll
    for (int j = 0; j < 8; ++j) {
        int c  = j * 256 + tid;
        int n  = c >> 5, kk = c & 31;
        int ks = kk >> 2, kq = kk & 3;
        int sw = (n & 15) ^ kq ^ ((ks & 1) << 2);
        uint4 d = *(const uint4*)(W + n * 256 + kk * 8);
        *(uint4*)&Bl[ks * 2048 + (n >> 4) * 512 + kq * 128 + sw * 8] = d;
    }
    __syncthreads();

    int row0 = l * 256 + wave * 64;
    const unsigned short* arow = ctxg + (size_t)(row0 + l16) * D_ + quad * 8;

    f32x4_t acc[4][4];
#pragma unroll
    for (int mt = 0; mt < 4; ++mt)
#pragma unroll
        for (int nt = 0; nt < 4; ++nt) acc[mt][nt] = (f32x4_t){0.f,0.f,0.f,0.f};

    bf16x8_t a_cur[4], a_nxt[4];
#pragma unroll
    for (int mt = 0; mt < 4; ++mt) a_cur[mt] = *(const bf16x8_t*)(arow + mt * 16 * D_);

    int swb = l16 ^ quad;
#pragma unroll
    for (int ks = 0; ks < 8; ++ks) {
        if (ks < 7) {
#pragma unroll
            for (int mt = 0; mt < 4; ++mt)
                a_nxt[mt] = *(const bf16x8_t*)(arow + mt * 16 * D_ + (ks + 1) * 32);
        }
        int kbase = ks * 2048 + quad * 128 + (swb ^ ((ks & 1) << 2)) * 8;
        __builtin_amdgcn_s_setprio(1);
#pragma unroll
        for (int nt = 0; nt < 4; ++nt) {
            bf16x8_t bfr = *(const bf16x8_t*)&Bl[kbase + nt * 512];
#pragma unroll
            for (int mt = 0; mt < 4; ++mt)
                acc[mt][nt] = __builtin_amdgcn_mfma_f32_16x16x32_bf16(a_cur[mt], bfr, acc[mt][nt], 0, 0, 0);
        }
        __builtin_amdgcn_s_setprio(0);
#pragma unroll
        for (int mt = 0; mt < 4; ++mt) a_cur[mt] = a_nxt[mt];
    }
    __syncthreads();   // all waves done reading Bl before T overwrites it

    // bias for this thread's fixed n-slot (c4 = tid & 15)
    float4 b4 = ((const float4*)(bo + n0))[tid & 15];

#pragma unroll
    for (int half = 0; half < 2; ++half) {
        if ((wave >> 1) == half) {
            int sl0 = (wave & 1) * 64;
#pragma unroll
            for (int mt = 0; mt < 4; ++mt)
#pragma unroll
                for (int nt = 0; nt < 4; ++nt)
#pragma unroll
                    for (int r = 0; r < 4; ++r) {
                        int sl = sl0 + mt * 16 + quad * 4 + r;
                        T[sl * 68 + nt * 16 + l16] = acc[mt][nt][r];
                    }
        }
        __syncthreads();
#pragma unroll
        for (int i = 0; i < 8; ++i) {
            int idx = i * 256 + tid;
            int sl = idx >> 4, c4 = idx & 15;
            float4 v = *(float4*)&T[sl * 68 + c4 * 4];
            v.x += b4.x; v.y += b4.y; v.z += b4.z; v.w += b4.w;
            *(float4*)&out[((size_t)(half * 128 + sl) * L_NR + l) * D_ + n0 + c4 * 4] = v;
        }
        if (half == 0) __syncthreads();   // T dead before half-1 overwrite
    }
}

extern "C" void kernel_launch(void* const* d_in, const int* in_sizes, int n_in,
                              void* d_out, int out_size, void* d_ws, size_t ws_size,
                              hipStream_t stream) {
    const float* m     = (const float*)d_in[0];
    const int* seq_pad = (const int*)d_in[1];
    const int* res_pad = (const int*)d_in[2];
    const float* lns   = (const float*)d_in[3];
    const float* lnb   = (const float*)d_in[4];
    const float* wq    = (const float*)d_in[5];
    const float* wk    = (const float*)d_in[6];
    const float* wv    = (const float*)d_in[7];
    const float* wg    = (const float*)d_in[8];
    const float* bg    = (const float*)d_in[9];
    const float* wo    = (const float*)d_in[10];
    const float* bo    = (const float*)d_in[11];
    float* out         = (float*)d_out;

    const size_t NE = (size_t)L_NR * S_NS * D_;   // 12,582,912 elements
    unsigned short* xn   = (unsigned short*)d_ws; // bf16 (L,S,D)
    unsigned short* ctxg = xn + NE;               // bf16 (L,S,D) gated context
    unsigned short* wbf  = ctxg + NE;             // 5 x 65536 bf16 weights

    ln_convw_kernel<<<12288 + 320, 256, 0, stream>>>(m, lns, lnb, xn,
                                                     wq, wk, wv, wg, wo, wbf);
    fused_kernel<<<L_NR * H_, 512, 0, stream>>>(xn, wbf, bg, seq_pad, res_pad, ctxg);
    out_kernel<<<dim3(192, 4), 256, 0, stream>>>(ctxg, wbf + 4 * 65536, bo, out);
}

// Round 13
// 192.594 us; speedup vs baseline: 1.0298x; 1.0298x over previous
//
#include <hip/hip_runtime.h>
#include <stdint.h>

#define L_NR 192
#define S_NS 256
#define D_   256
#define H_   8
#define C_   32

typedef __bf16    bf16x8_t __attribute__((ext_vector_type(8)));
typedef _Float16  half4_t  __attribute__((ext_vector_type(4)));
typedef float     f32x4_t  __attribute__((ext_vector_type(4)));

__device__ __forceinline__ float bflo(unsigned int u) { return __uint_as_float(u << 16); }
__device__ __forceinline__ unsigned int f2b(float f) {
    unsigned int x = __float_as_uint(f);
    return (x + 0x7fffu + ((x >> 16) & 1u)) >> 16;   // RNE
}
__device__ __forceinline__ unsigned short f2h(float f) {
    union { _Float16 h; unsigned short u; } cv; cv.h = (_Float16)f; return cv.u;
}

// ---- LayerNorm (blocks 0..12287) + weight bf16 conversion (blocks 12288..12607) ----
__global__ __launch_bounds__(256) void ln_convw_kernel(
    const float* __restrict__ m,
    const float* __restrict__ lns,
    const float* __restrict__ lnb,
    unsigned short* __restrict__ xn,
    const float* __restrict__ wq, const float* __restrict__ wk,
    const float* __restrict__ wv, const float* __restrict__ wg,
    const float* __restrict__ wo, unsigned short* __restrict__ wbf)
{
    int tid = threadIdx.x;
    int b = blockIdx.x;

    if (b >= 12288) {                       // ---- convw part ----
        int cb  = b - 12288;                // 0..319
        int mat = cb >> 6;                  // 64 blocks per matrix
        int bx  = cb & 63;
        const float* src = (mat == 0) ? wq : (mat == 1) ? wk : (mat == 2) ? wv
                         : (mat == 3) ? wg : wo;
        int i = (bx * 256 + tid) * 4;
        float4 v = *(const float4*)(src + i);
        uint2 w;
        w.x = f2b(v.x) | (f2b(v.y) << 16);
        w.y = f2b(v.z) | (f2b(v.w) << 16);
        *(uint2*)(wbf + (size_t)mat * 65536 + i) = w;
        return;
    }

    // ---- layernorm part: m fp32 (S,L,D) -> xn bf16 (L,S,D) ----
    int lane = tid & 63, wave = tid >> 6;
    int r = b * 4 + wave;                   // r = s*L + l
    int s = r / L_NR, l = r % L_NR;

    float4 x = ((const float4*)(m + (size_t)r * D_))[lane];

    float sum = x.x + x.y + x.z + x.w;
    float ss  = x.x*x.x + x.y*x.y + x.z*x.z + x.w*x.w;
#pragma unroll
    for (int off = 32; off > 0; off >>= 1) {
        sum += __shfl_xor(sum, off, 64);
        ss  += __shfl_xor(ss,  off, 64);
    }
    float mean = sum * (1.0f/256.0f);
    float var  = ss  * (1.0f/256.0f) - mean * mean;
    float rstd = rsqrtf(fmaxf(var, 0.0f) + 1e-5f);

    float4 sc = ((const float4*)lns)[lane];
    float4 bi = ((const float4*)lnb)[lane];

    float y0 = (x.x - mean) * rstd * sc.x + bi.x;
    float y1 = (x.y - mean) * rstd * sc.y + bi.y;
    float y2 = (x.z - mean) * rstd * sc.z + bi.z;
    float y3 = (x.w - mean) * rstd * sc.w + bi.w;

    uint2 w;
    w.x = f2b(y0) | (f2b(y1) << 16);
    w.y = f2b(y2) | (f2b(y3) << 16);
    *(uint2*)(xn + ((size_t)l * S_NS + s) * D_ + lane * 4) = w;
}

// ------------- Fused projections + attention per (l,h) -------------
// Round-12 (resubmitted; round-12 bench was an infra failure, same as r9):
// selective revert of round-11. The flagall if/else DUPLICATED exp loop
// pushed the attn phase's arch-register need over the 64-reg half of the
// (512,4) split -> scratch spill (FETCH 14.5->31.6MB, WRITE 24.6->83.7MB,
// dur +3.4us). Reverted to the single masked loop (round-10 form, exactly 64
// arch VGPR, zero headroom there). KEPT: g==0 specialization (fewer ops) and
// setprio in this kernel (2 blocks/CU at different phases = T5 regime).
// Bit-identical -> absmax must stay 0.004882812.
// Spill tripwire: FETCH must return to ~14.5 MB.
#define QP 40    // Q/K LDS row stride (bf16 elems)
#define VP 264   // V^T LDS row stride (f16 elems)
#define VXOR(c) (((((c) >> 3) & 3)) << 4)

__global__ __launch_bounds__(512, 4) void fused_kernel(
    const unsigned short* __restrict__ xn,
    const unsigned short* __restrict__ wbf,   // 4 matrices, bf16, 65536 each
    const float* __restrict__ bg,
    const int* __restrict__ seq_pad, const int* __restrict__ res_pad,
    unsigned short* __restrict__ ctxg)
{
    __shared__ __align__(16) unsigned char SM[65536];   // union: Bst | {Q,K,V}
    __shared__ unsigned int padm[16];

    unsigned short* Bst  = (unsigned short*)SM;               // 65536 B (GEMM phase)
    unsigned short* Qlds = (unsigned short*)SM;               // 20480 B (attn phase)
    unsigned short* Klds = (unsigned short*)(SM + 20480);     // 20480 B
    unsigned short* Vlds = (unsigned short*)(SM + 40960);     // 16896 B (ends 57856)

    int tid  = threadIdx.x;
    int lane = tid & 63, wave = tid >> 6;       // 8 waves
    int quad = lane >> 4, l16 = lane & 15;

    // XCD regroup: the 8 h-blocks of one l are consecutive slots on ONE XCD.
    int hw   = blockIdx.x;
    int xcd  = hw & 7, slot = hw >> 3;
    int h    = slot & 7;
    int l    = (slot >> 3) * 8 + xcd;

    if (tid < 16) {
        unsigned int pm = 0;
        for (int mt = 0; mt < 16; ++mt)
            pm |= (seq_pad[mt * 16 + tid] != 0 ? 1u : 0u) << mt;
        padm[tid] = pm;
    }

    int row0 = l * 256 + wave * 32;
    const unsigned short* arow = xn + (size_t)(row0 + l16) * D_ + quad * 8;

    // early A prefetch for ks=0 (completes during staging)
    bf16x8_t a_cur[2], a_nxt[2];
    a_cur[0] = *(const bf16x8_t*)(arow);
    a_cur[1] = *(const bf16x8_t*)(arow + 16 * D_);

    // stage all 4 B tiles (32 n x 256 k each): coalesced global, swizzled LDS
    const unsigned short* Wh = wbf + (size_t)(h * 32) * 256;
#pragma unroll
    for (int j = 0; j < 8; ++j) {
        int mat = j >> 1;
        int c  = (j & 1) * 512 + tid;
        int n  = c >> 5, kk = c & 31;
        int ks = kk >> 2, kq = kk & 3;
        int sw = (n & 15) ^ kq ^ ((ks & 1) << 2);
        uint4 d = *(const uint4*)(Wh + (size_t)mat * 65536 + n * 256 + kk * 8);
        *(uint4*)&Bst[mat * 8192 + ks * 1024 + (n >> 4) * 512 + kq * 128 + sw * 8] = d;
    }
    __syncthreads();

    f32x4_t acc[4][2][2];
#pragma unroll
    for (int mat = 0; mat < 4; ++mat)
#pragma unroll
        for (int mt = 0; mt < 2; ++mt)
#pragma unroll
            for (int nt = 0; nt < 2; ++nt) acc[mat][mt][nt] = (f32x4_t){0.f,0.f,0.f,0.f};

    int swb = l16 ^ quad;
#pragma unroll
    for (int ks = 0; ks < 8; ++ks) {
        if (ks < 7) {
            a_nxt[0] = *(const bf16x8_t*)(arow + (ks + 1) * 32);
            a_nxt[1] = *(const bf16x8_t*)(arow + 16 * D_ + (ks + 1) * 32);
        }
        int kbase = ks * 1024 + quad * 128 + (swb ^ ((ks & 1) << 2)) * 8;
        __builtin_amdgcn_s_setprio(1);
#pragma unroll
        for (int mat = 0; mat < 4; ++mat) {
#pragma unroll
            for (int nt = 0; nt < 2; ++nt) {
                bf16x8_t bfr = *(const bf16x8_t*)&Bst[mat * 8192 + kbase + nt * 512];
                acc[mat][0][nt] = __builtin_amdgcn_mfma_f32_16x16x32_bf16(a_cur[0], bfr, acc[mat][0][nt], 0, 0, 0);
                acc[mat][1][nt] = __builtin_amdgcn_mfma_f32_16x16x32_bf16(a_cur[1], bfr, acc[mat][1][nt], 0, 0, 0);
            }
        }
        __builtin_amdgcn_s_setprio(0);
        a_cur[0] = a_nxt[0]; a_cur[1] = a_nxt[1];
    }
    __syncthreads();   // ALL waves done reading Bst before Q/K/V overwrite it

    // ---- epilogues: write Q/K/V into the union region + gate regs ----
    const float qscale = 0.17677669529663687f;  // 1/sqrt(32)
    f32x4_t accg[2][2];

#pragma unroll
    for (int mt = 0; mt < 2; ++mt)
#pragma unroll
        for (int nt = 0; nt < 2; ++nt) {
#pragma unroll
            for (int r = 0; r < 4; ++r) {
                int srow = wave * 32 + mt * 16 + quad * 4 + r;
                Qlds[srow * QP + nt * 16 + l16] = (unsigned short)f2b(acc[0][mt][nt][r] * qscale);
                Klds[srow * QP + nt * 16 + l16] = (unsigned short)f2b(acc[1][mt][nt][r]);
            }
            // V: f16, transposed + swizzled, b64 packed
            int cc = nt * 16 + l16;
            int s0 = wave * 32 + mt * 16 + quad * 4;
            half4_t hv;
            hv[0] = (_Float16)acc[2][mt][nt][0];
            hv[1] = (_Float16)acc[2][mt][nt][1];
            hv[2] = (_Float16)acc[2][mt][nt][2];
            hv[3] = (_Float16)acc[2][mt][nt][3];
            *(half4_t*)&Vlds[cc * VP + (s0 ^ VXOR(cc))] = hv;
            // G: sigmoid, round through bf16, keep in regs
            float bgn = bg[h * 32 + nt * 16 + l16];
#pragma unroll
            for (int r = 0; r < 4; ++r)
                accg[mt][nt][r] = bflo(f2b(1.0f / (1.0f + __expf(-(acc[3][mt][nt][r] + bgn)))));
        }
    __syncthreads();   // K/V/Q (cross-wave) complete before attention reads

    // ---------------- attention (2 qt x 16 rows/wave, online softmax) ----
    unsigned int allm = 0xFFFFu;
#pragma unroll
    for (int i = 0; i < 16; ++i) allm &= padm[i];
    int flagall = (res_pad[l] != 0) || (allm == 0xFFFFu);

    unsigned int keep[4];
#pragma unroll
    for (int r = 0; r < 4; ++r)
        keep[r] = flagall ? 0xFFFFu : (~padm[quad * 4 + r] & 0xFFFFu);

    const float LOG2E = 1.4426950408889634f;
    int vx0 = VXOR(l16), vx1 = VXOR(16 + l16);

#pragma unroll
    for (int qt = 0; qt < 2; ++qt) {
        int sb = wave * 32 + qt * 16;

        bf16x8_t qf = *(const bf16x8_t*)(Qlds + (size_t)(sb + l16) * QP + quad * 8);

        float mk = -3.0e38f;
        float sp = 0.0f;
        f32x4_t c0 = (f32x4_t){0.f,0.f,0.f,0.f}, c1 = (f32x4_t){0.f,0.f,0.f,0.f};

#pragma unroll
        for (int g = 0; g < 2; ++g) {
            f32x4_t a[8];
            __builtin_amdgcn_s_setprio(1);
#pragma unroll
            for (int j = 0; j < 8; ++j) {
                int kt = g * 8 + j;
                bf16x8_t kf = *(const bf16x8_t*)(Klds + (kt * 16 + l16) * QP + quad * 8);
                a[j] = __builtin_amdgcn_mfma_f32_16x16x32_bf16(kf, qf, (f32x4_t){0.f,0.f,0.f,0.f}, 0, 0, 0);
            }
            __builtin_amdgcn_s_setprio(0);
            float p0 = fmaxf(fmaxf(a[0][0], a[0][1]), fmaxf(a[0][2], a[0][3]));
            float p1 = fmaxf(fmaxf(a[1][0], a[1][1]), fmaxf(a[1][2], a[1][3]));
            float p2 = fmaxf(fmaxf(a[2][0], a[2][1]), fmaxf(a[2][2], a[2][3]));
            float p3 = fmaxf(fmaxf(a[3][0], a[3][1]), fmaxf(a[3][2], a[3][3]));
            float p4 = fmaxf(fmaxf(a[4][0], a[4][1]), fmaxf(a[4][2], a[4][3]));
            float p5 = fmaxf(fmaxf(a[5][0], a[5][1]), fmaxf(a[5][2], a[5][3]));
            float p6 = fmaxf(fmaxf(a[6][0], a[6][1]), fmaxf(a[6][2], a[6][3]));
            float p7 = fmaxf(fmaxf(a[7][0], a[7][1]), fmaxf(a[7][2], a[7][3]));
            float gm = fmaxf(fmaxf(fmaxf(p0, p1), fmaxf(p2, p3)),
                             fmaxf(fmaxf(p4, p5), fmaxf(p6, p7)));
            gm = fmaxf(gm, __shfl_xor(gm, 16, 64));
            gm = fmaxf(gm, __shfl_xor(gm, 32, 64));
            float gmk = gm * LOG2E;

            if (g == 0) {
                // first group: c0/c1/sp are zero; old path multiplied them by
                // exp2(-3e38-gmk)==0 — equivalent to just adopting gmk.
                mk = gmk;
            } else {
                bool need = gmk > mk + 11.0f;
                if (__any(need)) {
                    float nmk = fmaxf(mk, gmk);
                    float f = __builtin_amdgcn_exp2f(mk - nmk);
                    mk = nmk;
                    sp *= f;
#pragma unroll
                    for (int r = 0; r < 4; ++r) {
                        float fr = __shfl(f, (lane & 48) | (quad * 4 + r), 64);
                        c0[r] *= fr; c1[r] *= fr;
                    }
                }
            }

            // single masked exp loop (round-10 form: exactly fits 64 arch VGPRs)
            half4_t pf[8];
            float s0 = 0.f, s1 = 0.f, s2 = 0.f, s3 = 0.f;
#pragma unroll
            for (int j = 0; j < 8; ++j) {
                int kt = g * 8 + j;
                float e0 = __builtin_amdgcn_exp2f(a[j][0] * LOG2E - mk);
                float e1 = __builtin_amdgcn_exp2f(a[j][1] * LOG2E - mk);
                float e2 = __builtin_amdgcn_exp2f(a[j][2] * LOG2E - mk);
                float e3 = __builtin_amdgcn_exp2f(a[j][3] * LOG2E - mk);
                e0 = ((keep[0] >> kt) & 1u) ? e0 : 0.0f;
                e1 = ((keep[1] >> kt) & 1u) ? e1 : 0.0f;
                e2 = ((keep[2] >> kt) & 1u) ? e2 : 0.0f;
                e3 = ((keep[3] >> kt) & 1u) ? e3 : 0.0f;
                s0 += e0; s1 += e1; s2 += e2; s3 += e3;
                half4_t t;
                t[0] = (_Float16)e0; t[1] = (_Float16)e1;
                t[2] = (_Float16)e2; t[3] = (_Float16)e3;
                pf[j] = t;
            }
            sp += (s0 + s1) + (s2 + s3);

            __builtin_amdgcn_s_setprio(1);
#pragma unroll
            for (int j = 0; j < 8; ++j) {
                int kt = g * 8 + j;
                int toff = kt * 16 + quad * 4;
                half4_t v0 = *(const half4_t*)(Vlds + l16 * VP        + (toff ^ vx0));
                half4_t v1 = *(const half4_t*)(Vlds + (16 + l16) * VP + (toff ^ vx1));
                c0 = __builtin_amdgcn_mfma_f32_16x16x16f16(pf[j], v0, c0, 0, 0, 0);
                c1 = __builtin_amdgcn_mfma_f32_16x16x16f16(pf[j], v1, c1, 0, 0, 0);
            }
            __builtin_amdgcn_s_setprio(0);
        }

        sp += __shfl_xor(sp, 16, 64);
        sp += __shfl_xor(sp, 32, 64);
        float inv = 1.0f / sp;

#pragma unroll
        for (int r = 0; r < 4; ++r) {
            int s = sb + quad * 4 + r;
            float iv = __shfl(inv, (lane & 48) | (quad * 4 + r), 64);
            float g0 = accg[qt][0][r];
            float g1 = accg[qt][1][r];
            unsigned short* op = ctxg + (size_t)(l * S_NS + s) * D_ + h * C_;
            op[l16]      = (unsigned short)f2b(c0[r] * iv * g0);
            op[16 + l16] = (unsigned short)f2b(c1[r] * iv * g1);
        }
    }
}

// ------------- Output projection (LDS-B): ctxg @ wo^T + bo -> out fp32 (S,L,D) -------------
// Round-9 structure; setprio removed (lockstep GEMM = m190's harmful regime).
__global__ __launch_bounds__(256, 4) void out_kernel(
    const unsigned short* __restrict__ ctxg,
    const unsigned short* __restrict__ wob,   // bf16 wo
    const float* __restrict__ bo,
    float* __restrict__ out)
{
    __shared__ __align__(16) unsigned char OSM[34816];   // union: B (32KB) | T [128][68] f32
    unsigned short* Bl = (unsigned short*)OSM;
    float*          T  = (float*)OSM;

    int tid  = threadIdx.x;
    int lane = tid & 63, wave = tid >> 6;
    int quad = lane >> 4, l16 = lane & 15;

    // --- XCD regroup: invert hw = l%8 + 8*((l/8)*4 + y) ---
    int hw   = blockIdx.y * 192 + blockIdx.x;   // dispatch index (x-fastest)
    int xcd  = hw & 7;
    int slot = hw >> 3;
    int y    = slot & 3;
    int l    = (slot >> 2) * 8 + xcd;

    int n0   = y * 64;
    const unsigned short* W = wob + (size_t)n0 * 256;

#pragma unroll
    for (int j = 0; j < 8; ++j) {
        int c  = j * 256 + tid;
        int n  = c >> 5, kk = c & 31;
        int ks = kk >> 2, kq = kk & 3;
        int sw = (n & 15) ^ kq ^ ((ks & 1) << 2);
        uint4 d = *(const uint4*)(W + n * 256 + kk * 8);
        *(uint4*)&Bl[ks * 2048 + (n >> 4) * 512 + kq * 128 + sw * 8] = d;
    }
    __syncthreads();

    int row0 = l * 256 + wave * 64;
    const unsigned short* arow = ctxg + (size_t)(row0 + l16) * D_ + quad * 8;

    f32x4_t acc[4][4];
#pragma unroll
    for (int mt = 0; mt < 4; ++mt)
#pragma unroll
        for (int nt = 0; nt < 4; ++nt) acc[mt][nt] = (f32x4_t){0.f,0.f,0.f,0.f};

    bf16x8_t a_cur[4], a_nxt[4];
#pragma unroll
    for (int mt = 0; mt < 4; ++mt) a_cur[mt] = *(const bf16x8_t*)(arow + mt * 16 * D_);

    int swb = l16 ^ quad;
#pragma unroll
    for (int ks = 0; ks < 8; ++ks) {
        if (ks < 7) {
#pragma unroll
            for (int mt = 0; mt < 4; ++mt)
                a_nxt[mt] = *(const bf16x8_t*)(arow + mt * 16 * D_ + (ks + 1) * 32);
        }
        int kbase = ks * 2048 + quad * 128 + (swb ^ ((ks & 1) << 2)) * 8;
#pragma unroll
        for (int nt = 0; nt < 4; ++nt) {
            bf16x8_t bfr = *(const bf16x8_t*)&Bl[kbase + nt * 512];
#pragma unroll
            for (int mt = 0; mt < 4; ++mt)
                acc[mt][nt] = __builtin_amdgcn_mfma_f32_16x16x32_bf16(a_cur[mt], bfr, acc[mt][nt], 0, 0, 0);
        }
#pragma unroll
        for (int mt = 0; mt < 4; ++mt) a_cur[mt] = a_nxt[mt];
    }
    __syncthreads();   // all waves done reading Bl before T overwrites it

    // bias for this thread's fixed n-slot (c4 = tid & 15)
    float4 b4 = ((const float4*)(bo + n0))[tid & 15];

#pragma unroll
    for (int half = 0; half < 2; ++half) {
        if ((wave >> 1) == half) {
            int sl0 = (wave & 1) * 64;
#pragma unroll
            for (int mt = 0; mt < 4; ++mt)
#pragma unroll
                for (int nt = 0; nt < 4; ++nt)
#pragma unroll
                    for (int r = 0; r < 4; ++r) {
                        int sl = sl0 + mt * 16 + quad * 4 + r;
                        T[sl * 68 + nt * 16 + l16] = acc[mt][nt][r];
                    }
        }
        __syncthreads();
#pragma unroll
        for (int i = 0; i < 8; ++i) {
            int idx = i * 256 + tid;
            int sl = idx >> 4, c4 = idx & 15;
            float4 v = *(float4*)&T[sl * 68 + c4 * 4];
            v.x += b4.x; v.y += b4.y; v.z += b4.z; v.w += b4.w;
            *(float4*)&out[((size_t)(half * 128 + sl) * L_NR + l) * D_ + n0 + c4 * 4] = v;
        }
        if (half == 0) __syncthreads();   // T dead before half-1 overwrite
    }
}

extern "C" void kernel_launch(void* const* d_in, const int* in_sizes, int n_in,
                              void* d_out, int out_size, void* d_ws, size_t ws_size,
                              hipStream_t stream) {
    const float* m     = (const float*)d_in[0];
    const int* seq_pad = (const int*)d_in[1];
    const int* res_pad = (const int*)d_in[2];
    const float* lns   = (const float*)d_in[3];
    const float* lnb   = (const float*)d_in[4];
    const float* wq    = (const float*)d_in[5];
    const float* wk    = (const float*)d_in[6];
    const float* wv    = (const float*)d_in[7];
    const float* wg    = (const float*)d_in[8];
    const float* bg    = (const float*)d_in[9];
    const float* wo    = (const float*)d_in[10];
    const float* bo    = (const float*)d_in[11];
    float* out         = (float*)d_out;

    const size_t NE = (size_t)L_NR * S_NS * D_;   // 12,582,912 elements
    unsigned short* xn   = (unsigned short*)d_ws; // bf16 (L,S,D)
    unsigned short* ctxg = xn + NE;               // bf16 (L,S,D) gated context
    unsigned short* wbf  = ctxg + NE;             // 5 x 65536 bf16 weights

    ln_convw_kernel<<<12288 + 320, 256, 0, stream>>>(m, lns, lnb, xn,
                                                     wq, wk, wv, wg, wo, wbf);
    fused_kernel<<<L_NR * H_, 512, 0, stream>>>(xn, wbf, bg, seq_pad, res_pad, ctxg);
    out_kernel<<<dim3(192, 4), 256, 0, stream>>>(ctxg, wbf + 4 * 65536, bo, out);
}